// Round 13
// baseline (84.618 us; speedup 1.0000x reference)
//
#include <hip/hip_runtime.h>

// Packed-sequence LSTM (B=4096, T=512, D=18, H=8) + Linear(8->1) head.
//
// R13 = R12 (best: 78.9us; 16-step windows, producer/consumer wave split)
// + ONE delta: the PRODUCER's x-dot goes through inline-asm v_pk_fma_f32
// (36 scalar FMA -> 18 packed per row). Consumer untouched (R11 showed asm
// on the consumer's serial chain regresses: copies on the critical path).
// Model: the block's 2 waves share SIMD issue (window wall ~5900cy ~= sum
// of both waves' issue, not max); cutting producer issue by ~576cy/window
// attacks that directly. R11 already proved this producer code correct.
//
// Structure recap (R12): Producer window I: DMA chunks {2I+4,2I+5} (18 ops),
// vmcnt(18) retires {2I+2,2I+3} (issued one window ago), produce both,
// lgkm(0), s_barrier. Consumer window I: consume chunks {2I,2I+1} (16
// steps; 1 ds_read_b64/step prefetched 1 ahead, first read after barrier),
// DPP-only cross-lane, batched y stores, s_barrier. Raw s_barrier only
// (never __syncthreads - it drains vmcnt). No stores on producer wave ->
// vmcnt counts exact.

namespace {

constexpr int NT = 512;
constexpr int ND = 18;
constexpr float LOG2E = 1.4426950408889634f;

typedef float v2f __attribute__((ext_vector_type(2)));
typedef float v4f __attribute__((ext_vector_type(4)));

template <int C>
__device__ __forceinline__ float fdpp(float v) {
    const int i = __float_as_int(v);
    return __int_as_float(__builtin_amdgcn_update_dpp(i, i, C, 0xF, 0xF, true));
}
__device__ __forceinline__ void gload_lds(const void* g, void* l) {
    __builtin_amdgcn_global_load_lds(
        (const __attribute__((address_space(1))) void*)g,
        (__attribute__((address_space(3))) void*)l, 4, 0, 0);
}
// Packed f32 FMA (VOP3P, default op_sel). Non-volatile -> schedulable.
__device__ __forceinline__ v2f pkfma(v2f a, v2f b, v2f c) {
    v2f d;
    asm("v_pk_fma_f32 %0, %1, %2, %3" : "=v"(d) : "v"(a), "v"(b), "v"(c));
    return d;
}

__global__ __launch_bounds__(128, 1) void lstm_pc(
    const float* __restrict__ x, const int* __restrict__ lengths,
    const float* __restrict__ W_ih, const float* __restrict__ W_hh,
    const float* __restrict__ b_ih, const float* __restrict__ b_hh,
    const float* __restrict__ W_lin, const float* __restrict__ b_lin,
    float* __restrict__ out)
{
    // A ring: 32 row slots (row r -> slot r&31), [seq][elem0..15].
    // B ring: 4 chunk blocks, [row-in-chunk][seq][elem16..17].
    // XG ring: 4 chunk buffers, [t-in-chunk][gate-pair][seq(+1 pad)] of v2f.
    __shared__ __align__(16) float Aring[32][4][16];
    __shared__ __align__(16) float Bring[4][8][4][2];
    __shared__ __align__(16) v2f   XG[4][8][16][5];

    const int tid  = (int)threadIdx.x;
    const int wav  = tid >> 6;          // 0 = consumer, 1 = producer
    const int w    = tid & 63;
    const int grp  = w >> 4;            // seq within block
    const int l16  = w & 15;
    const int p    = l16 >> 3;          // half: 0 -> {i,g}, 1 -> {f,o}
    const int j    = l16 & 7;           // hidden unit
    const int lenmax = lengths[blockIdx.x * 4];       // sorted desc
    const int nwin = (lenmax + 15) >> 4;              // 16-step windows
    const int rowA = j + (p ? 8 : 0);   // p0: i, p1: f
    const int rowB = j + (p ? 24 : 16); // p0: g, p1: o

    if (wav == 1) {
        // ============================ PRODUCER ============================
        v2f wxA[9], wxB[9];
        {
            const v2f* ra = (const v2f*)(W_ih + rowA * ND);
            const v2f* rb = (const v2f*)(W_ih + rowB * ND);
#pragma unroll
            for (int k = 0; k < 9; ++k) { wxA[k] = ra[k]; wxB[k] = rb[k]; }
        }
        const float biasA = b_ih[rowA] + b_hh[rowA];
        const float biasB = b_ih[rowB] + b_hh[rowB];

        // DMA source lanes: A-op: seq w>>4, elem w&15 (row uniform).
        // B-op: row w>>3, seq (w>>1)&3, elem 16+(w&1); dest linear = lane.
        const char* xc = (const char*)x;
        const char* pA = xc + (size_t)((((unsigned)(blockIdx.x * 4 + (w >> 4)) * (NT * ND))
                                       + (unsigned)(w & 15)) * 4u);
        const char* pB = xc + (size_t)((((unsigned)(blockIdx.x * 4 + ((w >> 1) & 3)) * (NT * ND))
                                       + 16u + (unsigned)(w & 1)) * 4u);
        const unsigned rB0 = (unsigned)(w >> 3);

        auto dma_chunk = [&](int dd) {
            const int r0 = dd * 8;
#pragma unroll
            for (int k = 0; k < 8; ++k) {
                const int rr = (r0 + k < NT) ? (r0 + k) : (NT - 1);
                gload_lds(pA + (unsigned)rr * 72u, &Aring[(r0 + k) & 31][0][0]);
            }
            unsigned rb = (unsigned)r0 + rB0;
            rb = (rb < (unsigned)NT) ? rb : (unsigned)(NT - 1);
            gload_lds(pB + rb * 72u, &Bring[dd & 3][0][0][0]);
        };

        // produce: packed FMA (R11-proven producer arithmetic), compiler-
        // scheduled loads (R9 lesson: no hand pipelining).
        auto produce_chunk = [&](int cc) {
            const int s0 = (cc * 8) & 31;
            const int bf = cc & 3;
#pragma unroll
            for (int k = 0; k < 8; ++k) {
                const v4f* ap = (const v4f*)&Aring[s0 + k][grp][0];
                const v4f q0 = ap[0], q1 = ap[1], q2 = ap[2], q3 = ap[3];
                const v2f bt = *(const v2f*)&Bring[bf][k][grp][0];
                v2f aA = pkfma(q0.lo, wxA[0], v2f{biasA, 0.f});
                v2f aB = pkfma(q0.lo, wxB[0], v2f{biasB, 0.f});
                aA = pkfma(q0.hi, wxA[1], aA);  aB = pkfma(q0.hi, wxB[1], aB);
                aA = pkfma(q1.lo, wxA[2], aA);  aB = pkfma(q1.lo, wxB[2], aB);
                aA = pkfma(q1.hi, wxA[3], aA);  aB = pkfma(q1.hi, wxB[3], aB);
                aA = pkfma(q2.lo, wxA[4], aA);  aB = pkfma(q2.lo, wxB[4], aB);
                aA = pkfma(q2.hi, wxA[5], aA);  aB = pkfma(q2.hi, wxB[5], aB);
                aA = pkfma(q3.lo, wxA[6], aA);  aB = pkfma(q3.lo, wxB[6], aB);
                aA = pkfma(q3.hi, wxA[7], aA);  aB = pkfma(q3.hi, wxB[7], aB);
                aA = pkfma(bt,    wxA[8], aA);  aB = pkfma(bt,    wxB[8], aB);
                XG[bf][k][l16][grp] = v2f{aA.x + aA.y, aB.x + aB.y};
            }
        };

        // prologue: DMA chunks 0..3 (36 ops); {0,1} ready after vmcnt(18)
        dma_chunk(0); dma_chunk(1); dma_chunk(2); dma_chunk(3);
        asm volatile("s_waitcnt vmcnt(18)" ::: "memory");
        produce_chunk(0);
        produce_chunk(1);
        asm volatile("s_waitcnt lgkmcnt(0)" ::: "memory");
        __builtin_amdgcn_sched_barrier(0);
        __builtin_amdgcn_s_barrier();
        __builtin_amdgcn_sched_barrier(0);

        for (int I = 0; I < nwin; ++I) {
            dma_chunk(2 * I + 4);
            dma_chunk(2 * I + 5);
            asm volatile("s_waitcnt vmcnt(18)" ::: "memory");
            produce_chunk(2 * I + 2);
            produce_chunk(2 * I + 3);
            asm volatile("s_waitcnt lgkmcnt(0)" ::: "memory");
            __builtin_amdgcn_sched_barrier(0);
            __builtin_amdgcn_s_barrier();
            __builtin_amdgcn_sched_barrier(0);
        }
    } else {
        // ============================ CONSUMER ============================
        const int len = lengths[blockIdx.x * 4 + grp];

        // DPP self-calibration: which h-index does row_ror:r deliver here?
        int idx[8];
        idx[0] = j;
        idx[1] = __builtin_amdgcn_update_dpp(0, j, 0x121, 0xF, 0xF, true) & 7;
        idx[2] = __builtin_amdgcn_update_dpp(0, j, 0x122, 0xF, 0xF, true) & 7;
        idx[3] = __builtin_amdgcn_update_dpp(0, j, 0x123, 0xF, 0xF, true) & 7;
        idx[4] = __builtin_amdgcn_update_dpp(0, j, 0x124, 0xF, 0xF, true) & 7;
        idx[5] = __builtin_amdgcn_update_dpp(0, j, 0x125, 0xF, 0xF, true) & 7;
        idx[6] = __builtin_amdgcn_update_dpp(0, j, 0x126, 0xF, 0xF, true) & 7;
        idx[7] = __builtin_amdgcn_update_dpp(0, j, 0x127, 0xF, 0xF, true) & 7;

        v2f whA[4], whB[4], wl2[4];
#pragma unroll
        for (int r = 0; r < 4; ++r) {
            whA[r] = v2f{W_hh[rowA * 8 + idx[2 * r]], W_hh[rowA * 8 + idx[2 * r + 1]]};
            whB[r] = v2f{W_hh[rowB * 8 + idx[2 * r]], W_hh[rowB * 8 + idx[2 * r + 1]]};
            wl2[r] = v2f{W_lin[idx[2 * r]], W_lin[idx[2 * r + 1]]};
        }
        const float bl = b_lin[0];
        // vB exponent scale: p0 computes tanh(g)=2*sigma(2g)-1, p1 sigma(o)
        const float Kp = p ? -LOG2E : -2.0f * LOG2E;

        float* yb = out + (size_t)(blockIdx.x * 4 + grp) * NT;

        v2f hp[4] = {v2f{0.f, 0.f}, v2f{0.f, 0.f}, v2f{0.f, 0.f}, v2f{0.f, 0.f}};
        float c_ = 0.0f, hown = 0.0f;

        __builtin_amdgcn_s_barrier();           // pairs with producer prologue
        __builtin_amdgcn_sched_barrier(0);

        for (int I = 0; I < nwin; ++I) {
            const int t = I * 16;
            const v2f* xg0 = &XG[(2 * I) & 3][0][l16][grp];      // step stride 80 v2f
            const v2f* xg1 = &XG[(2 * I + 1) & 3][0][l16][grp];
            float y[16];
            v2f xgn = xg0[0];   // first read AFTER barrier (writer was last window)
#pragma unroll
            for (int k = 0; k < 16; ++k) {
                const v2f xgc = xgn;
                if (k < 15) xgn = (k + 1 < 8) ? xg0[(k + 1) * 80] : xg1[(k + 1 - 8) * 80];

                // recurrent dots
                v2f tA = hp[0] * whA[0];
                tA = hp[1] * whA[1] + tA;
                tA = hp[2] * whA[2] + tA;
                tA = hp[3] * whA[3] + tA;
                v2f tB = hp[0] * whB[0];
                tB = hp[1] * whB[1] + tB;
                tB = hp[2] * whB[2] + tB;
                tB = hp[3] * whB[3] + tB;
                const float aA = (xgc.x + tA.x) + tA.y;
                const float aB = (xgc.y + tB.x) + tB.y;

                // activations: vA = sigma(i|f); vB = p0 tanh(g), p1 sigma(o)
                const float vA = __builtin_amdgcn_rcpf(
                    1.0f + __builtin_amdgcn_exp2f(aA * -LOG2E));
                const float sB = __builtin_amdgcn_rcpf(
                    1.0f + __builtin_amdgcn_exp2f(aB * Kp));
                const float vB = p ? sB : fmaf(2.0f, sB, -1.0f);

                // half exchange via ror:8; unmasked cell update
                const float send1 = p ? vA : (vA * vB);
                const float ex1 = fdpp<0x128>(send1);
                const float f_ = p ? send1 : ex1;
                const float ig_ = p ? ex1 : send1;
                c_ = fmaf(f_, c_, ig_);
                const float tc = fmaf(-2.0f, __builtin_amdgcn_rcpf(
                    1.0f + __builtin_amdgcn_exp2f(c_ * (2.0f * LOG2E))), 1.0f);
                const float ex2 = fdpp<0x128>(vB);
                const float o_ = p ? vB : ex2;
                hown = o_ * tc;

                // h rotations -> pairs
                const float h1 = fdpp<0x121>(hown);
                const float h2 = fdpp<0x122>(hown);
                const float h3 = fdpp<0x123>(hown);
                const float h4 = fdpp<0x124>(hown);
                const float h5 = fdpp<0x125>(hown);
                const float h6 = fdpp<0x126>(hown);
                const float h7 = fdpp<0x127>(hown);
                hp[0] = v2f{hown, h1}; hp[1] = v2f{h2, h3};
                hp[2] = v2f{h4, h5};   hp[3] = v2f{h6, h7};

                // linear head (off the critical chain)
                v2f ya = hp[0] * wl2[0];
                ya = hp[1] * wl2[1] + ya;
                ya = hp[2] * wl2[2] + ya;
                ya = hp[3] * wl2[3] + ya;
                y[k] = (ya.x + ya.y) + bl;
            }

            if (l16 == 0) {
                if (t + 15 < len) {
                    *(v4f*)(yb + t)      = v4f{y[0],  y[1],  y[2],  y[3]};
                    *(v4f*)(yb + t + 4)  = v4f{y[4],  y[5],  y[6],  y[7]};
                    *(v4f*)(yb + t + 8)  = v4f{y[8],  y[9],  y[10], y[11]};
                    *(v4f*)(yb + t + 12) = v4f{y[12], y[13], y[14], y[15]};
                } else {
#pragma unroll
                    for (int k = 0; k < 16; ++k)
                        if (t + k < len) yb[t + k] = y[k];
                }
            }
            __builtin_amdgcn_sched_barrier(0);
            __builtin_amdgcn_s_barrier();
            __builtin_amdgcn_sched_barrier(0);
        }
    }
}

} // namespace

extern "C" void kernel_launch(void* const* d_in, const int* in_sizes, int n_in,
                              void* d_out, int out_size, void* d_ws, size_t ws_size,
                              hipStream_t stream) {
    const float* x     = (const float*)d_in[0];
    const int*   lens  = (const int*)d_in[1];
    const float* W_ih  = (const float*)d_in[2];
    const float* W_hh  = (const float*)d_in[3];
    const float* b_ih  = (const float*)d_in[4];
    const float* b_hh  = (const float*)d_in[5];
    const float* W_lin = (const float*)d_in[6];
    const float* b_lin = (const float*)d_in[7];
    float* out = (float*)d_out;

    // zero the padded region (kernel only writes t < len)
    hipMemsetAsync(out, 0, (size_t)4096 * NT * sizeof(float), stream);

    lstm_pc<<<1024, 128, 0, stream>>>(x, lens, W_ih, W_hh, b_ih, b_hh,
                                      W_lin, b_lin, out);
}

// Round 14
// 75.939 us; speedup vs baseline: 1.1143x; 1.1143x over previous
//
#include <hip/hip_runtime.h>

// Packed-sequence LSTM (B=4096, T=512, D=18, H=8) + Linear(8->1) head.
//
// R14 = R12 (proven best: 78.9us; 16-step windows, producer/consumer wave
// split, plain compiler-scheduled v2f math - pkfma is permanently reverted,
// it regressed in BOTH R11 and R13) + ONE correctness-neutral delta:
//   Length-balanced block->sequence-group swizzle.
// Evidence: block 0's intrinsic cost is ~33us but wall is 79us. With
// round-robin dispatch the CU hosting block 0 (len 512) also hosts blocks
// ~256/512/768 -> per-CU consumer work 512+384+256+128 = 1280 step-units
// (the max; other CUs as low as 770). Remap rounds to {q, 1023-q, 256+q,
// 767-q} (bijective): every CU's 4 blocks sum to ~1024 step-units and the
// longest block shares its CU with a near-empty one. Dispatch->CU mapping
// is undefined per the ISA docs - this is a perf heuristic only; each block
// still computes its own sequences correctly.
//
// Structure recap (R12): Producer window I: DMA chunks {2I+4,2I+5} (18 ops),
// vmcnt(18) retires {2I+2,2I+3} (issued one window ago, ~4800cy > HBM
// latency), produce both (plain v2f, compiler-scheduled), lgkm(0),
// s_barrier. Consumer window I: consume chunks {2I,2I+1}, 16 steps, 1
// ds_read_b64/step prefetched 1 ahead (first read after barrier), DPP-only
// cross-lane (ror:8 exchange; ror:1..7 h-rotation with rotation-ordered
// weights via runtime DPP self-calibration), batched y stores, s_barrier.
// Raw s_barrier only (never __syncthreads - it drains vmcnt). Producer wave
// has no stores -> vmcnt counts exact.

namespace {

constexpr int NT = 512;
constexpr int ND = 18;
constexpr float LOG2E = 1.4426950408889634f;

typedef float v2f __attribute__((ext_vector_type(2)));
typedef float v4f __attribute__((ext_vector_type(4)));

template <int C>
__device__ __forceinline__ float fdpp(float v) {
    const int i = __float_as_int(v);
    return __int_as_float(__builtin_amdgcn_update_dpp(i, i, C, 0xF, 0xF, true));
}
__device__ __forceinline__ void gload_lds(const void* g, void* l) {
    __builtin_amdgcn_global_load_lds(
        (const __attribute__((address_space(1))) void*)g,
        (__attribute__((address_space(3))) void*)l, 4, 0, 0);
}

__global__ __launch_bounds__(128, 1) void lstm_pc(
    const float* __restrict__ x, const int* __restrict__ lengths,
    const float* __restrict__ W_ih, const float* __restrict__ W_hh,
    const float* __restrict__ b_ih, const float* __restrict__ b_hh,
    const float* __restrict__ W_lin, const float* __restrict__ b_lin,
    float* __restrict__ out)
{
    // A ring: 32 row slots (row r -> slot r&31), [seq][elem0..15].
    // B ring: 4 chunk blocks, [row-in-chunk][seq][elem16..17].
    // XG ring: 4 chunk buffers, [t-in-chunk][gate-pair][seq(+1 pad)] of v2f.
    __shared__ __align__(16) float Aring[32][4][16];
    __shared__ __align__(16) float Bring[4][8][4][2];
    __shared__ __align__(16) v2f   XG[4][8][16][5];

    // Length-balanced swizzle: CU hosting round-slot q gets groups
    // {q, 1023-q, 256+q, 767-q} -> per-CU work ~constant (~1024 step-units).
    const int q_ = (int)blockIdx.x & 255;
    const int r_ = (int)blockIdx.x >> 8;
    const int g  = (r_ == 0) ? q_ : (r_ == 1) ? (1023 - q_)
                 : (r_ == 2) ? (256 + q_) : (767 - q_);

    const int tid  = (int)threadIdx.x;
    const int wav  = tid >> 6;          // 0 = consumer, 1 = producer
    const int w    = tid & 63;
    const int grp  = w >> 4;            // seq within block
    const int l16  = w & 15;
    const int p    = l16 >> 3;          // half: 0 -> {i,g}, 1 -> {f,o}
    const int j    = l16 & 7;           // hidden unit
    const int lenmax = lengths[g * 4];  // sorted desc -> block max
    const int nwin = (lenmax + 15) >> 4;              // 16-step windows
    const int rowA = j + (p ? 8 : 0);   // p0: i, p1: f
    const int rowB = j + (p ? 24 : 16); // p0: g, p1: o

    if (wav == 1) {
        // ============================ PRODUCER ============================
        v2f wxA[9], wxB[9];
        {
            const v2f* ra = (const v2f*)(W_ih + rowA * ND);
            const v2f* rb = (const v2f*)(W_ih + rowB * ND);
#pragma unroll
            for (int k = 0; k < 9; ++k) { wxA[k] = ra[k]; wxB[k] = rb[k]; }
        }
        const float biasA = b_ih[rowA] + b_hh[rowA];
        const float biasB = b_ih[rowB] + b_hh[rowB];

        // DMA source lanes: A-op: seq w>>4, elem w&15 (row uniform).
        // B-op: row w>>3, seq (w>>1)&3, elem 16+(w&1); dest linear = lane.
        const char* xc = (const char*)x;
        const char* pA = xc + (size_t)((((unsigned)(g * 4 + (w >> 4)) * (NT * ND))
                                       + (unsigned)(w & 15)) * 4u);
        const char* pB = xc + (size_t)((((unsigned)(g * 4 + ((w >> 1) & 3)) * (NT * ND))
                                       + 16u + (unsigned)(w & 1)) * 4u);
        const unsigned rB0 = (unsigned)(w >> 3);

        auto dma_chunk = [&](int dd) {
            const int r0 = dd * 8;
#pragma unroll
            for (int k = 0; k < 8; ++k) {
                const int rr = (r0 + k < NT) ? (r0 + k) : (NT - 1);
                gload_lds(pA + (unsigned)rr * 72u, &Aring[(r0 + k) & 31][0][0]);
            }
            unsigned rb = (unsigned)r0 + rB0;
            rb = (rb < (unsigned)NT) ? rb : (unsigned)(NT - 1);
            gload_lds(pB + rb * 72u, &Bring[dd & 3][0][0][0]);
        };

        // plain compiler-scheduled produce (R9/R11/R13 lesson: no hand-tune)
        auto produce_chunk = [&](int cc) {
            const int s0 = (cc * 8) & 31;
            const int bf = cc & 3;
#pragma unroll
            for (int k = 0; k < 8; ++k) {
                const v4f* ap = (const v4f*)&Aring[s0 + k][grp][0];
                const v4f q0 = ap[0], q1 = ap[1], q2 = ap[2], q3 = ap[3];
                const v2f bt = *(const v2f*)&Bring[bf][k][grp][0];
                v2f aA = v2f{biasA, 0.f}, aB = v2f{biasB, 0.f};
                aA = q0.lo * wxA[0] + aA;  aB = q0.lo * wxB[0] + aB;
                aA = q0.hi * wxA[1] + aA;  aB = q0.hi * wxB[1] + aB;
                aA = q1.lo * wxA[2] + aA;  aB = q1.lo * wxB[2] + aB;
                aA = q1.hi * wxA[3] + aA;  aB = q1.hi * wxB[3] + aB;
                aA = q2.lo * wxA[4] + aA;  aB = q2.lo * wxB[4] + aB;
                aA = q2.hi * wxA[5] + aA;  aB = q2.hi * wxB[5] + aB;
                aA = q3.lo * wxA[6] + aA;  aB = q3.lo * wxB[6] + aB;
                aA = q3.hi * wxA[7] + aA;  aB = q3.hi * wxB[7] + aB;
                aA = bt * wxA[8] + aA;     aB = bt * wxB[8] + aB;
                XG[bf][k][l16][grp] = v2f{aA.x + aA.y, aB.x + aB.y};
            }
        };

        // prologue: DMA chunks 0..3 (36 ops); {0,1} ready after vmcnt(18)
        dma_chunk(0); dma_chunk(1); dma_chunk(2); dma_chunk(3);
        asm volatile("s_waitcnt vmcnt(18)" ::: "memory");
        produce_chunk(0);
        produce_chunk(1);
        asm volatile("s_waitcnt lgkmcnt(0)" ::: "memory");
        __builtin_amdgcn_sched_barrier(0);
        __builtin_amdgcn_s_barrier();
        __builtin_amdgcn_sched_barrier(0);

        for (int I = 0; I < nwin; ++I) {
            dma_chunk(2 * I + 4);
            dma_chunk(2 * I + 5);
            asm volatile("s_waitcnt vmcnt(18)" ::: "memory");
            produce_chunk(2 * I + 2);
            produce_chunk(2 * I + 3);
            asm volatile("s_waitcnt lgkmcnt(0)" ::: "memory");
            __builtin_amdgcn_sched_barrier(0);
            __builtin_amdgcn_s_barrier();
            __builtin_amdgcn_sched_barrier(0);
        }
    } else {
        // ============================ CONSUMER ============================
        const int len = lengths[g * 4 + grp];

        // DPP self-calibration: which h-index does row_ror:r deliver here?
        int idx[8];
        idx[0] = j;
        idx[1] = __builtin_amdgcn_update_dpp(0, j, 0x121, 0xF, 0xF, true) & 7;
        idx[2] = __builtin_amdgcn_update_dpp(0, j, 0x122, 0xF, 0xF, true) & 7;
        idx[3] = __builtin_amdgcn_update_dpp(0, j, 0x123, 0xF, 0xF, true) & 7;
        idx[4] = __builtin_amdgcn_update_dpp(0, j, 0x124, 0xF, 0xF, true) & 7;
        idx[5] = __builtin_amdgcn_update_dpp(0, j, 0x125, 0xF, 0xF, true) & 7;
        idx[6] = __builtin_amdgcn_update_dpp(0, j, 0x126, 0xF, 0xF, true) & 7;
        idx[7] = __builtin_amdgcn_update_dpp(0, j, 0x127, 0xF, 0xF, true) & 7;

        v2f whA[4], whB[4], wl2[4];
#pragma unroll
        for (int r = 0; r < 4; ++r) {
            whA[r] = v2f{W_hh[rowA * 8 + idx[2 * r]], W_hh[rowA * 8 + idx[2 * r + 1]]};
            whB[r] = v2f{W_hh[rowB * 8 + idx[2 * r]], W_hh[rowB * 8 + idx[2 * r + 1]]};
            wl2[r] = v2f{W_lin[idx[2 * r]], W_lin[idx[2 * r + 1]]};
        }
        const float bl = b_lin[0];
        // vB exponent scale: p0 computes tanh(g)=2*sigma(2g)-1, p1 sigma(o)
        const float Kp = p ? -LOG2E : -2.0f * LOG2E;

        float* yb = out + (size_t)(g * 4 + grp) * NT;

        v2f hp[4] = {v2f{0.f, 0.f}, v2f{0.f, 0.f}, v2f{0.f, 0.f}, v2f{0.f, 0.f}};
        float c_ = 0.0f, hown = 0.0f;

        __builtin_amdgcn_s_barrier();           // pairs with producer prologue
        __builtin_amdgcn_sched_barrier(0);

        for (int I = 0; I < nwin; ++I) {
            const int t = I * 16;
            const v2f* xg0 = &XG[(2 * I) & 3][0][l16][grp];      // step stride 80 v2f
            const v2f* xg1 = &XG[(2 * I + 1) & 3][0][l16][grp];
            float y[16];
            v2f xgn = xg0[0];   // first read AFTER barrier (writer was last window)
#pragma unroll
            for (int k = 0; k < 16; ++k) {
                const v2f xgc = xgn;
                if (k < 15) xgn = (k + 1 < 8) ? xg0[(k + 1) * 80] : xg1[(k + 1 - 8) * 80];

                // recurrent dots
                v2f tA = hp[0] * whA[0];
                tA = hp[1] * whA[1] + tA;
                tA = hp[2] * whA[2] + tA;
                tA = hp[3] * whA[3] + tA;
                v2f tB = hp[0] * whB[0];
                tB = hp[1] * whB[1] + tB;
                tB = hp[2] * whB[2] + tB;
                tB = hp[3] * whB[3] + tB;
                const float aA = (xgc.x + tA.x) + tA.y;
                const float aB = (xgc.y + tB.x) + tB.y;

                // activations: vA = sigma(i|f); vB = p0 tanh(g), p1 sigma(o)
                const float vA = __builtin_amdgcn_rcpf(
                    1.0f + __builtin_amdgcn_exp2f(aA * -LOG2E));
                const float sB = __builtin_amdgcn_rcpf(
                    1.0f + __builtin_amdgcn_exp2f(aB * Kp));
                const float vB = p ? sB : fmaf(2.0f, sB, -1.0f);

                // half exchange via ror:8; unmasked cell update
                const float send1 = p ? vA : (vA * vB);
                const float ex1 = fdpp<0x128>(send1);
                const float f_ = p ? send1 : ex1;
                const float ig_ = p ? ex1 : send1;
                c_ = fmaf(f_, c_, ig_);
                const float tc = fmaf(-2.0f, __builtin_amdgcn_rcpf(
                    1.0f + __builtin_amdgcn_exp2f(c_ * (2.0f * LOG2E))), 1.0f);
                const float ex2 = fdpp<0x128>(vB);
                const float o_ = p ? vB : ex2;
                hown = o_ * tc;

                // h rotations -> pairs
                const float h1 = fdpp<0x121>(hown);
                const float h2 = fdpp<0x122>(hown);
                const float h3 = fdpp<0x123>(hown);
                const float h4 = fdpp<0x124>(hown);
                const float h5 = fdpp<0x125>(hown);
                const float h6 = fdpp<0x126>(hown);
                const float h7 = fdpp<0x127>(hown);
                hp[0] = v2f{hown, h1}; hp[1] = v2f{h2, h3};
                hp[2] = v2f{h4, h5};   hp[3] = v2f{h6, h7};

                // linear head (off the critical chain)
                v2f ya = hp[0] * wl2[0];
                ya = hp[1] * wl2[1] + ya;
                ya = hp[2] * wl2[2] + ya;
                ya = hp[3] * wl2[3] + ya;
                y[k] = (ya.x + ya.y) + bl;
            }

            if (l16 == 0) {
                if (t + 15 < len) {
                    *(v4f*)(yb + t)      = v4f{y[0],  y[1],  y[2],  y[3]};
                    *(v4f*)(yb + t + 4)  = v4f{y[4],  y[5],  y[6],  y[7]};
                    *(v4f*)(yb + t + 8)  = v4f{y[8],  y[9],  y[10], y[11]};
                    *(v4f*)(yb + t + 12) = v4f{y[12], y[13], y[14], y[15]};
                } else {
#pragma unroll
                    for (int k = 0; k < 16; ++k)
                        if (t + k < len) yb[t + k] = y[k];
                }
            }
            __builtin_amdgcn_sched_barrier(0);
            __builtin_amdgcn_s_barrier();
            __builtin_amdgcn_sched_barrier(0);
        }
    }
}

} // namespace

extern "C" void kernel_launch(void* const* d_in, const int* in_sizes, int n_in,
                              void* d_out, int out_size, void* d_ws, size_t ws_size,
                              hipStream_t stream) {
    const float* x     = (const float*)d_in[0];
    const int*   lens  = (const int*)d_in[1];
    const float* W_ih  = (const float*)d_in[2];
    const float* W_hh  = (const float*)d_in[3];
    const float* b_ih  = (const float*)d_in[4];
    const float* b_hh  = (const float*)d_in[5];
    const float* W_lin = (const float*)d_in[6];
    const float* b_lin = (const float*)d_in[7];
    float* out = (float*)d_out;

    // zero the padded region (kernel only writes t < len)
    hipMemsetAsync(out, 0, (size_t)4096 * NT * sizeof(float), stream);

    lstm_pc<<<1024, 128, 0, stream>>>(x, lens, W_ih, W_hh, b_ih, b_hh,
                                      W_lin, b_lin, out);
}